// Round 16
// baseline (443.613 us; speedup 1.0000x reference)
//
#include <hip/hip_runtime.h>

#define S_  5184
#define C_  768
#define NH_ 12
#define HD_ 64
#define FF_ 3072
#define WW_ 72

typedef __attribute__((ext_vector_type(8))) short bf16x8;
typedef __attribute__((ext_vector_type(4))) float f32x4;

__device__ __forceinline__ float bf2f(unsigned short u){
    unsigned int i = ((unsigned int)u) << 16; float f; __builtin_memcpy(&f,&i,4); return f;
}
__device__ __forceinline__ unsigned short f2bf(float f){
    unsigned int i; __builtin_memcpy(&i,&f,4);
    unsigned int r = (i + 0x7fffu + ((i>>16)&1u)) >> 16;
    return (unsigned short)r;
}
__device__ __forceinline__ float ldf(float v){ return v; }
__device__ __forceinline__ float ldf(unsigned short v){ return bf2f(v); }

__device__ __forceinline__ void gload16(const void* g, const void* l) {
    __builtin_amdgcn_global_load_lds((const __attribute__((address_space(1))) void*)g,
                                     (__attribute__((address_space(3))) void*)l, 16, 0, 0);
}
__device__ __forceinline__ unsigned int cvtpk(float lo, float hi){
    unsigned int r;
    asm volatile("v_cvt_pk_bf16_f32 %0, %1, %2" : "=v"(r) : "v"(lo), "v"(hi));
    return r;
}

// ---------------- LayerNorm ----------------
template<typename TIN>
__global__ __launch_bounds__(256) void ln_k(const TIN* __restrict__ x,
                                            const float* __restrict__ g,
                                            const float* __restrict__ b,
                                            unsigned short* __restrict__ out)
{
    int row = blockIdx.x, tid = threadIdx.x;
    const TIN* xr = x + (size_t)row * C_;
    float v0 = ldf(xr[tid]), v1 = ldf(xr[tid+256]), v2 = ldf(xr[tid+512]);
    float s = v0+v1+v2, q = v0*v0+v1*v1+v2*v2;
    #pragma unroll
    for (int off=32; off; off>>=1){ s += __shfl_xor(s,off); q += __shfl_xor(q,off); }
    __shared__ float ss[4], qq[4], mshare[2];
    int lane = tid & 63, wv = tid >> 6;
    if (!lane){ ss[wv] = s; qq[wv] = q; }
    __syncthreads();
    if (!tid){
        float S2 = ss[0]+ss[1]+ss[2]+ss[3];
        float Q2 = qq[0]+qq[1]+qq[2]+qq[3];
        float mean = S2 * (1.f/C_);
        float var  = Q2 * (1.f/C_) - mean*mean;
        mshare[0] = mean; mshare[1] = rsqrtf(var + 1e-6f);
    }
    __syncthreads();
    float mean = mshare[0], inv = mshare[1];
    unsigned short* orow = out + (size_t)row * C_;
    orow[tid]     = f2bf((v0-mean)*inv*g[tid]     + b[tid]);
    orow[tid+256] = f2bf((v1-mean)*inv*g[tid+256] + b[tid+256]);
    orow[tid+512] = f2bf((v2-mean)*inv*g[tid+512] + b[tid+512]);
}

// ---------------- RoPE (tables inline, loops heads; q scaled 0.125*log2e) ----------------
__global__ __launch_bounds__(256) void rope_k(unsigned short* __restrict__ q,
                                              unsigned short* __restrict__ k)
{
    int idx = blockIdx.x * 256 + threadIdx.x;   // over S_*32 (s, pair)
    if (idx >= S_*32) return;
    int s = idx >> 5, i = idx & 31;
    int hh = s / WW_, ww = s % WW_;
    int m = i & 15;
    float coord = (i < 16) ? (float)hh : (float)ww;
    float freq = powf(10000.0f, -(float)m / 16.0f);
    float a = coord * freq;
    float c = cosf(a), sn = sinf(a);
    const float QS = 0.18033688011112042f;   // 0.125 * log2(e)
    #pragma unroll
    for (int h = 0; h < NH_; h++) {
        size_t base = (size_t)s*C_ + h*HD_ + 2*i;
        float x0 = bf2f(q[base]), x1 = bf2f(q[base+1]);
        q[base]   = f2bf((x0*c - x1*sn) * QS);
        q[base+1] = f2bf((x1*c + x0*sn) * QS);
        x0 = bf2f(k[base]); x1 = bf2f(k[base+1]);
        k[base]   = f2bf(x0*c - x1*sn);
        k[base+1] = f2bf(x1*c + x0*sn);
    }
}

// ---------------- Fused weight transposes: all 6 weights, one launch ----------------
__global__ __launch_bounds__(256) void transpose_all(const float* __restrict__ wq, unsigned short* __restrict__ wqT,
                                                     const float* __restrict__ wk, unsigned short* __restrict__ wkT,
                                                     const float* __restrict__ wv, unsigned short* __restrict__ wvT,
                                                     const float* __restrict__ wo, unsigned short* __restrict__ woT,
                                                     const float* __restrict__ wf1, unsigned short* __restrict__ wf1T,
                                                     const float* __restrict__ wf2, unsigned short* __restrict__ wf2T)
{
    __shared__ float t[32][33];
    int b = blockIdx.x;
    const float* W; unsigned short* WT; int K, N, tb;
    if      (b < 576)  { W = wq;  WT = wqT;  K = 768;  N = 768;  tb = b; }
    else if (b < 1152) { W = wk;  WT = wkT;  K = 768;  N = 768;  tb = b - 576; }
    else if (b < 1728) { W = wv;  WT = wvT;  K = 768;  N = 768;  tb = b - 1152; }
    else if (b < 2304) { W = wo;  WT = woT;  K = 768;  N = 768;  tb = b - 1728; }
    else if (b < 4608) { W = wf1; WT = wf1T; K = 768;  N = 3072; tb = b - 2304; }
    else               { W = wf2; WT = wf2T; K = 3072; N = 768;  tb = b - 4608; }
    int ntx = N / 32;
    int n0 = (tb % ntx) * 32, k0 = (tb / ntx) * 32;
    int tx = threadIdx.x & 31, ty = threadIdx.x >> 5;
    #pragma unroll
    for (int i = 0; i < 4; i++)
        t[ty + i*8][tx] = W[(size_t)(k0 + ty + i*8)*N + n0 + tx];
    __syncthreads();
    #pragma unroll
    for (int i = 0; i < 4; i++)
        WT[(size_t)(n0 + ty + i*8)*K + k0 + tx] = f2bf(t[tx][ty + i*8]);
}

// ---------------- MFMA GEMM, 2-phase double-buffered, XCD-swizzled ----------------
// lda = K-stride of A and BT (full K). EPI 5: split-K partial (blockIdx.z = K-half),
// bf16 partial to outp + z*M*N; A/BT advanced by z*K (loop-K passed = half).
template<int EPI, int NWC, int BK>
__global__ __launch_bounds__(256) void gemm_mfma(const unsigned short* __restrict__ A,
                                                 const unsigned short* __restrict__ BT,
                                                 const float* __restrict__ bias,
                                                 const float* __restrict__ biasB,
                                                 const float* __restrict__ biasC,
                                                 const float* __restrict__ scale,
                                                 const float* __restrict__ addend,
                                                 void* __restrict__ outp,
                                                 void* __restrict__ outp2,
                                                 int M, int N, int K, int lda)
{
    const int BN = 64*NWC;
    const int MI = (NWC == 2) ? 4 : 2;
    __shared__ __align__(16) unsigned short As[2][128*BK];
    __shared__ __align__(16) unsigned short Bs[2][64*NWC*BK];
    int tid = threadIdx.x;
    int w = tid >> 6, lane = tid & 63, lq = lane & 15, lk = lane >> 4;
    int wr = (NWC == 2) ? (w >> 1) : w;
    int wc = (NWC == 2) ? (w & 1) : 0;

    if (EPI == 5) {                       // split-K: advance into this half's K range
        A  += (size_t)blockIdx.z * K;
        BT += (size_t)blockIdx.z * K;
    }

    // XCD-bijective block swizzle (m204)
    int gx = gridDim.x;
    int nwg = gx * gridDim.y;
    int bid = blockIdx.y * gx + blockIdx.x;
    int xcd = bid & 7, idx = bid >> 3;
    int qq = nwg >> 3, rr = nwg & 7;
    int wg = (xcd < rr) ? (xcd*(qq+1) + idx) : (rr*(qq+1) + (xcd-rr)*qq + idx);
    int bm = (wg / gx) * 128, bn = (wg % gx) * BN;

    f32x4 acc[MI][4];
    #pragma unroll
    for (int i = 0; i < MI; i++)
        #pragma unroll
        for (int j = 0; j < 4; j++) acc[i][j] = 0;

    auto STAGE = [&](int buf, int kt) {
        #pragma unroll
        for (int u = 0; u < BK/16; u++) {
            int t = w*(BK/16) + u;
            int c = t*64 + lane;
            int kg = c >> 7, row = c & 127;
            int ra = bm + row; if (ra >= M) ra = M - 1;
            gload16(A + (size_t)ra*lda + kt*BK + kg*8, As[buf] + t*512);
        }
        #pragma unroll
        for (int u = 0; u < BK*NWC/32; u++) {
            int t = w*(BK*NWC/32) + u;
            int c = t*64 + lane;
            int kg = (NWC == 2) ? (c >> 7) : (c >> 6);
            int row = (NWC == 2) ? (c & 127) : (c & 63);
            gload16(BT + (size_t)(bn + row)*lda + kt*BK + kg*8, Bs[buf] + t*512);
        }
    };

    int nk = K / BK;
    STAGE(0, 0);
    int cur = 0;
    for (int kt = 0; kt < nk; kt++) {
        __syncthreads();
        if (kt + 1 < nk) STAGE(cur ^ 1, kt + 1);
        #pragma unroll
        for (int kk = 0; kk < BK/32; kk++) {
            bf16x8 af[MI], bfr[4];
            #pragma unroll
            for (int mi = 0; mi < MI; mi++)
                af[mi] = *(const bf16x8*)(As[cur] + (kk*4 + lk)*1024 + (wr*MI*16 + mi*16 + lq)*8);
            #pragma unroll
            for (int ni = 0; ni < 4; ni++)
                bfr[ni] = *(const bf16x8*)(Bs[cur] + (kk*4 + lk)*BN*8 + (wc*64 + ni*16 + lq)*8);
            #pragma unroll
            for (int mi = 0; mi < MI; mi++)
                #pragma unroll
                for (int ni = 0; ni < 4; ni++)
                    acc[mi][ni] = __builtin_amdgcn_mfma_f32_16x16x32_bf16(af[mi], bfr[ni], acc[mi][ni], 0, 0, 0);
        }
        cur ^= 1;
    }

    #pragma unroll
    for (int mi = 0; mi < MI; mi++) {
        #pragma unroll
        for (int ni = 0; ni < 4; ni++) {
            int n = bn + wc*64 + ni*16 + lq;
            int m0 = bm + wr*MI*16 + mi*16 + lk*4;
            if (EPI == 4) {
                if (n < 1536) {
                    const float* bb = (n < 768) ? bias : biasB;
                    int nn = (n < 768) ? n : (n - 768);
                    size_t base = (n < 768) ? 0 : ((size_t)S_ * 768);
                    #pragma unroll
                    for (int r = 0; r < 4; r++) {
                        int m = m0 + r;
                        if (m < M)
                            ((unsigned short*)outp)[base + (size_t)m*768 + nn] = f2bf(acc[mi][ni][r] + bb[nn]);
                    }
                } else {
                    if (m0 < M) {
                        float bv = biasC[n - 1536];
                        ushort4 pv;
                        pv.x = f2bf(acc[mi][ni][0] + bv);
                        pv.y = f2bf(acc[mi][ni][1] + bv);
                        pv.z = f2bf(acc[mi][ni][2] + bv);
                        pv.w = f2bf(acc[mi][ni][3] + bv);
                        *(ushort4*)((unsigned short*)outp2 + (size_t)(n - 1536)*S_ + m0) = pv;
                    }
                }
            } else if (EPI == 5) {
                unsigned short* pp = (unsigned short*)outp + (size_t)blockIdx.z * ((size_t)M * N);
                #pragma unroll
                for (int r = 0; r < 4; r++) {
                    int m = m0 + r;
                    if (m < M) pp[(size_t)m*N + n] = f2bf(acc[mi][ni][r]);
                }
            } else {
                #pragma unroll
                for (int r = 0; r < 4; r++) {
                    int m = m0 + r;
                    if (m < M) {
                        float v = acc[mi][ni][r] + bias[n];
                        if (EPI == 1) {
                            v = 0.5f * v * (1.f + erff(v * 0.70710678f));
                            ((unsigned short*)outp)[(size_t)m*N + n] = f2bf(v);
                        } else {
                            size_t o = (size_t)m*N + n;
                            ((float*)outp)[o] = v*scale[n] + addend[o];
                        }
                    }
                }
            }
        }
    }
}

// ---------------- split-K combine: out = (p0+p1+bias)*scale + addend ----------------
__global__ __launch_bounds__(256) void comb_k(const unsigned short* __restrict__ p,
                                              const float* __restrict__ bias,
                                              const float* __restrict__ scale,
                                              const float* __restrict__ addend,
                                              float* __restrict__ out)
{
    int gid = blockIdx.x * 256 + threadIdx.x;     // over S_*C_/4
    if (gid >= S_*C_/4) return;
    int n = (gid % (C_/4)) * 4;
    ushort4 a = ((const ushort4*)p)[gid];
    ushort4 b = ((const ushort4*)(p + (size_t)S_*C_))[gid];
    float4 ad = ((const float4*)addend)[gid];
    float4 o;
    o.x = (bf2f(a.x) + bf2f(b.x) + bias[n+0]) * scale[n+0] + ad.x;
    o.y = (bf2f(a.y) + bf2f(b.y) + bias[n+1]) * scale[n+1] + ad.y;
    o.z = (bf2f(a.z) + bf2f(b.z) + bias[n+2]) * scale[n+2] + ad.z;
    o.w = (bf2f(a.w) + bf2f(b.w) + bias[n+3]) * scale[n+3] + ad.w;
    ((float4*)out)[gid] = o;
}

// ---------------- MFMA flash attention v6 (165.5 us, 3x confirmed) ----------------
__global__ __launch_bounds__(256) void attn_mfma6(const unsigned short* __restrict__ Q,
                                                  const unsigned short* __restrict__ Kb,
                                                  const unsigned short* __restrict__ Vt,
                                                  unsigned short* __restrict__ O)
{
    __shared__ __align__(16) unsigned short Ks[2][4096];   // [dg][kv][8]
    __shared__ __align__(16) unsigned short Vs[2][4096];   // [kvg][d][8]
    int tid = threadIdx.x;
    int w = tid >> 6, lane = tid & 63, lq = lane & 15, lk = lane >> 4;
    int h = blockIdx.y;
    int q0 = blockIdx.x * 128 + w * 32;

    bf16x8 qf[2][2];
    #pragma unroll
    for (int qi = 0; qi < 2; qi++) {
        int qr = q0 + qi*16 + lq; if (qr >= S_) qr = S_ - 1;
        #pragma unroll
        for (int ks = 0; ks < 2; ks++)
            qf[qi][ks] = *(const bf16x8*)(Q + (size_t)qr*C_ + h*64 + ks*32 + lk*8);
    }

    union { bf16x8 v; unsigned int u[4]; } ones;
    ones.u[0] = 0x3F803F80u; ones.u[1] = 0x3F803F80u;
    ones.u[2] = 0x3F803F80u; ones.u[3] = 0x3F803F80u;

    f32x4 oacc[2][4];
    #pragma unroll
    for (int qi = 0; qi < 2; qi++)
        #pragma unroll
        for (int df = 0; df < 4; df++) oacc[qi][df] = 0;
    f32x4 lacc[2];
    lacc[0] = 0; lacc[1] = 0;

    auto STAGE = [&](int buf, int t) {
        int kv0 = t * 64;
        #pragma unroll
        for (int u = 0; u < 4; u++) {
            int tt = w*4 + u;
            if (tt < 8)
                gload16(Kb + (size_t)(kv0 + lane)*C_ + h*64 + tt*8, Ks[buf] + tt*512);
            else
                gload16(Vt + (size_t)(h*64 + lane)*S_ + kv0 + (tt-8)*8, Vs[buf] + (tt-8)*512);
        }
    };

    auto BODY = [&](int buf) {
        f32x4 s[2][4];
        #pragma unroll
        for (int qi = 0; qi < 2; qi++)
            #pragma unroll
            for (int nf = 0; nf < 4; nf++) s[qi][nf] = -8.0f;
        __builtin_amdgcn_s_setprio(1);
        #pragma unroll
        for (int ks = 0; ks < 2; ks++) {
            #pragma unroll
            for (int nf = 0; nf < 4; nf++) {
                bf16x8 kf = *(const bf16x8*)(Ks[buf] + (ks*4 + lk)*512 + (nf*16 + lq)*8);
                #pragma unroll
                for (int qi = 0; qi < 2; qi++)
                    s[qi][nf] = __builtin_amdgcn_mfma_f32_16x16x32_bf16(kf, qf[qi][ks], s[qi][nf], 0, 0, 0);
            }
        }
        __builtin_amdgcn_s_setprio(0);

        unsigned int pk[2][8];
        #pragma unroll
        for (int qi = 0; qi < 2; qi++) {
            #pragma unroll
            for (int nf = 0; nf < 4; nf++) {
                float p0 = exp2f(s[qi][nf][0]);
                float p1 = exp2f(s[qi][nf][1]);
                float p2 = exp2f(s[qi][nf][2]);
                float p3 = exp2f(s[qi][nf][3]);
                pk[qi][nf*2+0] = cvtpk(p0, p1);
                pk[qi][nf*2+1] = cvtpk(p2, p3);
            }
        }

        __builtin_amdgcn_s_setprio(1);
        #pragma unroll
        for (int ks = 0; ks < 2; ks++) {
            union { bf16x8 v; unsigned int u[4]; } pb[2];
            #pragma unroll
            for (int qi = 0; qi < 2; qi++) {
                pb[qi].u[0] = pk[qi][4*ks+0]; pb[qi].u[1] = pk[qi][4*ks+1];
                pb[qi].u[2] = pk[qi][4*ks+2]; pb[qi].u[3] = pk[qi][4*ks+3];
                lacc[qi] = __builtin_amdgcn_mfma_f32_16x16x32_bf16(ones.v, pb[qi].v, lacc[qi], 0, 0, 0);
            }
            #pragma unroll
            for (int df = 0; df < 4; df++) {
                int d = df*16 + lq;
                union { bf16x8 v; unsigned long long dd[2]; } va;
                va.dd[0] = *(const unsigned long long*)(Vs[buf] + (4*ks + (lk>>1))*512 + d*8 + (lk&1)*4);
                va.dd[1] = *(const unsigned long long*)(Vs[buf] + (4*ks + 2 + (lk>>1))*512 + d*8 + (lk&1)*4);
                #pragma unroll
                for (int qi = 0; qi < 2; qi++)
                    oacc[qi][df] = __builtin_amdgcn_mfma_f32_16x16x32_bf16(va.v, pb[qi].v, oacc[qi][df], 0, 0, 0);
            }
        }
        __builtin_amdgcn_s_setprio(0);
    };

    // NT = 81: 40 unrolled pairs + peeled tail
    STAGE(0, 0);
    #pragma unroll 1
    for (int t = 0; t < 80; t += 2) {
        __syncthreads();
        STAGE(1, t + 1);
        BODY(0);
        __syncthreads();
        STAGE(0, t + 2);        // t+2 <= 80 always valid
        BODY(1);
    }
    __syncthreads();
    BODY(0);                    // tile 80

    #pragma unroll
    for (int qi = 0; qi < 2; qi++) {
        int q = q0 + qi*16 + lq;
        if (q < S_) {
            float rl = 1.f / lacc[qi][0];
            #pragma unroll
            for (int df = 0; df < 4; df++) {
                ushort4 pv;
                pv.x = f2bf(oacc[qi][df][0] * rl);
                pv.y = f2bf(oacc[qi][df][1] * rl);
                pv.z = f2bf(oacc[qi][df][2] * rl);
                pv.w = f2bf(oacc[qi][df][3] * rl);
                *(ushort4*)(O + (size_t)q*C_ + h*64 + df*16 + lk*4) = pv;
            }
        }
    }
}

extern "C" void kernel_launch(void* const* d_in, const int* in_sizes, int n_in,
                              void* d_out, int out_size, void* d_ws, size_t ws_size,
                              hipStream_t stream)
{
    const float* hidden = (const float*)d_in[0];
    const float* wq  = (const float*)d_in[1];
    const float* bq  = (const float*)d_in[2];
    const float* wk  = (const float*)d_in[3];
    const float* bk  = (const float*)d_in[4];
    const float* wv  = (const float*)d_in[5];
    const float* bv  = (const float*)d_in[6];
    const float* wo  = (const float*)d_in[7];
    const float* bo  = (const float*)d_in[8];
    const float* g1  = (const float*)d_in[9];
    const float* b1  = (const float*)d_in[10];
    const float* g2  = (const float*)d_in[11];
    const float* b2  = (const float*)d_in[12];
    const float* wf1 = (const float*)d_in[13];
    const float* bf1 = (const float*)d_in[14];
    const float* wf2 = (const float*)d_in[15];
    const float* bf2_ = (const float*)d_in[16];
    const float* ls1 = (const float*)d_in[17];
    const float* ls2 = (const float*)d_in[18];

    char* ws = (char*)d_ws;
    size_t off = 0;
    auto alloc = [&](size_t bytes) { char* p = ws + off; off += (bytes + 255) & ~(size_t)255; return p; };

    float* res1          = (float*)alloc((size_t)S_*C_*4);
    unsigned short* lnb  = (unsigned short*)alloc((size_t)S_*C_*2);
    unsigned short* qb   = (unsigned short*)alloc((size_t)S_*C_*2);  // qb,kb contiguous (fused out)
    unsigned short* kb   = (unsigned short*)alloc((size_t)S_*C_*2);
    unsigned short* vtb  = (unsigned short*)alloc((size_t)S_*C_*2);  // V^T [C_][S_]
    unsigned short* ob   = (unsigned short*)alloc((size_t)S_*C_*2);
    unsigned short* fc1b = qb;   // alias qb..ob (4*S*C*2 == S*FF*2), dead by fc1
    unsigned short* wqT  = (unsigned short*)alloc((size_t)C_*C_*2);  // wqT,wkT,wvT contiguous
    unsigned short* wkT  = (unsigned short*)alloc((size_t)C_*C_*2);
    unsigned short* wvT  = (unsigned short*)alloc((size_t)C_*C_*2);
    unsigned short* woT  = (unsigned short*)alloc((size_t)C_*C_*2);
    unsigned short* wf1T = (unsigned short*)alloc((size_t)C_*FF_*2);
    unsigned short* wf2T = (unsigned short*)alloc((size_t)C_*FF_*2);
    unsigned short* pbuf = (unsigned short*)alloc((size_t)2*S_*C_*2); // split-K partials (16MB)
    float* outb = (float*)d_out;

    hipLaunchKernelGGL(transpose_all, dim3(6912), dim3(256), 0, stream,
                       wq, wqT, wk, wkT, wv, wvT, wo, woT, wf1, wf1T, wf2, wf2T);
    hipLaunchKernelGGL(ln_k<float>, dim3(S_), dim3(256), 0, stream, hidden, g1, b1, lnb);
    hipLaunchKernelGGL((gemm_mfma<4,2,32>), dim3(2304/128, 41), dim3(256), 0, stream,
                       lnb, wqT, bq, bk, bv, (const float*)nullptr, (const float*)nullptr,
                       (void*)qb, (void*)vtb, S_, 2304, C_, C_);
    hipLaunchKernelGGL(rope_k, dim3((S_*32 + 255)/256), dim3(256), 0, stream, qb, kb);
    hipLaunchKernelGGL(attn_mfma6, dim3((S_ + 127)/128, NH_), dim3(256), 0, stream,
                       qb, kb, vtb, ob);
    // o-proj: split-K=2 partials + combine (+ls1 + residual -> res1 f32)
    hipLaunchKernelGGL((gemm_mfma<5,1,64>), dim3(C_/64, 41, 2), dim3(256), 0, stream,
                       ob, woT, (const float*)nullptr, (const float*)nullptr, (const float*)nullptr,
                       (const float*)nullptr, (const float*)nullptr,
                       (void*)pbuf, (void*)nullptr, S_, C_, C_/2, C_);
    hipLaunchKernelGGL(comb_k, dim3((S_*C_/4 + 255)/256), dim3(256), 0, stream,
                       pbuf, bo, ls1, hidden, res1);
    hipLaunchKernelGGL(ln_k<float>, dim3(S_), dim3(256), 0, stream, res1, g2, b2, lnb);
    hipLaunchKernelGGL((gemm_mfma<1,2,32>), dim3(FF_/128, 41), dim3(256), 0, stream,
                       lnb, wf1T, bf1, (const float*)nullptr, (const float*)nullptr,
                       (const float*)nullptr, (const float*)nullptr,
                       (void*)fc1b, (void*)nullptr, S_, FF_, C_, C_);
    // fc2: split-K=2 partials + combine (+ls2 + residual -> d_out f32)
    hipLaunchKernelGGL((gemm_mfma<5,1,64>), dim3(C_/64, 41, 2), dim3(256), 0, stream,
                       fc1b, wf2T, (const float*)nullptr, (const float*)nullptr, (const float*)nullptr,
                       (const float*)nullptr, (const float*)nullptr,
                       (void*)pbuf, (void*)nullptr, S_, C_, FF_/2, FF_);
    hipLaunchKernelGGL(comb_k, dim3((S_*C_/4 + 255)/256), dim3(256), 0, stream,
                       pbuf, bf2_, ls2, res1, outb);
    (void)in_sizes; (void)n_in; (void)out_size; (void)ws_size;
}

// Round 17
// 425.929 us; speedup vs baseline: 1.0415x; 1.0415x over previous
//
#include <hip/hip_runtime.h>

#define S_  5184
#define C_  768
#define NH_ 12
#define HD_ 64
#define FF_ 3072
#define WW_ 72

typedef __attribute__((ext_vector_type(8))) short bf16x8;
typedef __attribute__((ext_vector_type(4))) float f32x4;

__device__ __forceinline__ float bf2f(unsigned short u){
    unsigned int i = ((unsigned int)u) << 16; float f; __builtin_memcpy(&f,&i,4); return f;
}
__device__ __forceinline__ unsigned short f2bf(float f){
    unsigned int i; __builtin_memcpy(&i,&f,4);
    unsigned int r = (i + 0x7fffu + ((i>>16)&1u)) >> 16;
    return (unsigned short)r;
}
__device__ __forceinline__ float ldf(float v){ return v; }
__device__ __forceinline__ float ldf(unsigned short v){ return bf2f(v); }

__device__ __forceinline__ void gload16(const void* g, const void* l) {
    __builtin_amdgcn_global_load_lds((const __attribute__((address_space(1))) void*)g,
                                     (__attribute__((address_space(3))) void*)l, 16, 0, 0);
}
__device__ __forceinline__ unsigned int cvtpk(float lo, float hi){
    unsigned int r;
    asm volatile("v_cvt_pk_bf16_f32 %0, %1, %2" : "=v"(r) : "v"(lo), "v"(hi));
    return r;
}

// ---------------- LayerNorm ----------------
template<typename TIN>
__global__ __launch_bounds__(256) void ln_k(const TIN* __restrict__ x,
                                            const float* __restrict__ g,
                                            const float* __restrict__ b,
                                            unsigned short* __restrict__ out)
{
    int row = blockIdx.x, tid = threadIdx.x;
    const TIN* xr = x + (size_t)row * C_;
    float v0 = ldf(xr[tid]), v1 = ldf(xr[tid+256]), v2 = ldf(xr[tid+512]);
    float s = v0+v1+v2, q = v0*v0+v1*v1+v2*v2;
    #pragma unroll
    for (int off=32; off; off>>=1){ s += __shfl_xor(s,off); q += __shfl_xor(q,off); }
    __shared__ float ss[4], qq[4], mshare[2];
    int lane = tid & 63, wv = tid >> 6;
    if (!lane){ ss[wv] = s; qq[wv] = q; }
    __syncthreads();
    if (!tid){
        float S2 = ss[0]+ss[1]+ss[2]+ss[3];
        float Q2 = qq[0]+qq[1]+qq[2]+qq[3];
        float mean = S2 * (1.f/C_);
        float var  = Q2 * (1.f/C_) - mean*mean;
        mshare[0] = mean; mshare[1] = rsqrtf(var + 1e-6f);
    }
    __syncthreads();
    float mean = mshare[0], inv = mshare[1];
    unsigned short* orow = out + (size_t)row * C_;
    orow[tid]     = f2bf((v0-mean)*inv*g[tid]     + b[tid]);
    orow[tid+256] = f2bf((v1-mean)*inv*g[tid+256] + b[tid+256]);
    orow[tid+512] = f2bf((v2-mean)*inv*g[tid+512] + b[tid+512]);
}

// ---------------- RoPE (tables inline, loops heads; q scaled 0.125*log2e) ----------------
__global__ __launch_bounds__(256) void rope_k(unsigned short* __restrict__ q,
                                              unsigned short* __restrict__ k)
{
    int idx = blockIdx.x * 256 + threadIdx.x;   // over S_*32 (s, pair)
    if (idx >= S_*32) return;
    int s = idx >> 5, i = idx & 31;
    int hh = s / WW_, ww = s % WW_;
    int m = i & 15;
    float coord = (i < 16) ? (float)hh : (float)ww;
    float freq = powf(10000.0f, -(float)m / 16.0f);
    float a = coord * freq;
    float c = cosf(a), sn = sinf(a);
    const float QS = 0.18033688011112042f;   // 0.125 * log2(e)
    #pragma unroll
    for (int h = 0; h < NH_; h++) {
        size_t base = (size_t)s*C_ + h*HD_ + 2*i;
        float x0 = bf2f(q[base]), x1 = bf2f(q[base+1]);
        q[base]   = f2bf((x0*c - x1*sn) * QS);
        q[base+1] = f2bf((x1*c + x0*sn) * QS);
        x0 = bf2f(k[base]); x1 = bf2f(k[base+1]);
        k[base]   = f2bf(x0*c - x1*sn);
        k[base+1] = f2bf(x1*c + x0*sn);
    }
}

// ---------------- Fused weight transposes: all 6 weights, one launch ----------------
__global__ __launch_bounds__(256) void transpose_all(const float* __restrict__ wq, unsigned short* __restrict__ wqT,
                                                     const float* __restrict__ wk, unsigned short* __restrict__ wkT,
                                                     const float* __restrict__ wv, unsigned short* __restrict__ wvT,
                                                     const float* __restrict__ wo, unsigned short* __restrict__ woT,
                                                     const float* __restrict__ wf1, unsigned short* __restrict__ wf1T,
                                                     const float* __restrict__ wf2, unsigned short* __restrict__ wf2T)
{
    __shared__ float t[32][33];
    int b = blockIdx.x;
    const float* W; unsigned short* WT; int K, N, tb;
    if      (b < 576)  { W = wq;  WT = wqT;  K = 768;  N = 768;  tb = b; }
    else if (b < 1152) { W = wk;  WT = wkT;  K = 768;  N = 768;  tb = b - 576; }
    else if (b < 1728) { W = wv;  WT = wvT;  K = 768;  N = 768;  tb = b - 1152; }
    else if (b < 2304) { W = wo;  WT = woT;  K = 768;  N = 768;  tb = b - 1728; }
    else if (b < 4608) { W = wf1; WT = wf1T; K = 768;  N = 3072; tb = b - 2304; }
    else               { W = wf2; WT = wf2T; K = 3072; N = 768;  tb = b - 4608; }
    int ntx = N / 32;
    int n0 = (tb % ntx) * 32, k0 = (tb / ntx) * 32;
    int tx = threadIdx.x & 31, ty = threadIdx.x >> 5;
    #pragma unroll
    for (int i = 0; i < 4; i++)
        t[ty + i*8][tx] = W[(size_t)(k0 + ty + i*8)*N + n0 + tx];
    __syncthreads();
    #pragma unroll
    for (int i = 0; i < 4; i++)
        WT[(size_t)(n0 + ty + i*8)*K + k0 + tx] = f2bf(t[tx][ty + i*8]);
}

// ---------------- MFMA GEMM, 2-phase double-buffered, XCD-swizzled (R10/R14 form, best measured) ----------------
template<int EPI, int NWC, int BK>
__global__ __launch_bounds__(256) void gemm_mfma(const unsigned short* __restrict__ A,
                                                 const unsigned short* __restrict__ BT,
                                                 const float* __restrict__ bias,
                                                 const float* __restrict__ biasB,
                                                 const float* __restrict__ biasC,
                                                 const float* __restrict__ scale,
                                                 const float* __restrict__ addend,
                                                 void* __restrict__ outp,
                                                 void* __restrict__ outp2,
                                                 int M, int N, int K)
{
    const int BN = 64*NWC;
    const int MI = (NWC == 2) ? 4 : 2;
    __shared__ __align__(16) unsigned short As[2][128*BK];
    __shared__ __align__(16) unsigned short Bs[2][64*NWC*BK];
    int tid = threadIdx.x;
    int w = tid >> 6, lane = tid & 63, lq = lane & 15, lk = lane >> 4;
    int wr = (NWC == 2) ? (w >> 1) : w;
    int wc = (NWC == 2) ? (w & 1) : 0;

    // XCD-bijective block swizzle (m204)
    int gx = gridDim.x;
    int nwg = gx * gridDim.y;
    int bid = blockIdx.y * gx + blockIdx.x;
    int xcd = bid & 7, idx = bid >> 3;
    int qq = nwg >> 3, rr = nwg & 7;
    int wg = (xcd < rr) ? (xcd*(qq+1) + idx) : (rr*(qq+1) + (xcd-rr)*qq + idx);
    int bm = (wg / gx) * 128, bn = (wg % gx) * BN;

    f32x4 acc[MI][4];
    #pragma unroll
    for (int i = 0; i < MI; i++)
        #pragma unroll
        for (int j = 0; j < 4; j++) acc[i][j] = 0;

    auto STAGE = [&](int buf, int kt) {
        #pragma unroll
        for (int u = 0; u < BK/16; u++) {
            int t = w*(BK/16) + u;
            int c = t*64 + lane;
            int kg = c >> 7, row = c & 127;
            int ra = bm + row; if (ra >= M) ra = M - 1;
            gload16(A + (size_t)ra*K + kt*BK + kg*8, As[buf] + t*512);
        }
        #pragma unroll
        for (int u = 0; u < BK*NWC/32; u++) {
            int t = w*(BK*NWC/32) + u;
            int c = t*64 + lane;
            int kg = (NWC == 2) ? (c >> 7) : (c >> 6);
            int row = (NWC == 2) ? (c & 127) : (c & 63);
            gload16(BT + (size_t)(bn + row)*K + kt*BK + kg*8, Bs[buf] + t*512);
        }
    };

    int nk = K / BK;
    STAGE(0, 0);
    int cur = 0;
    for (int kt = 0; kt < nk; kt++) {
        __syncthreads();
        if (kt + 1 < nk) STAGE(cur ^ 1, kt + 1);
        #pragma unroll
        for (int kk = 0; kk < BK/32; kk++) {
            bf16x8 af[MI], bfr[4];
            #pragma unroll
            for (int mi = 0; mi < MI; mi++)
                af[mi] = *(const bf16x8*)(As[cur] + (kk*4 + lk)*1024 + (wr*MI*16 + mi*16 + lq)*8);
            #pragma unroll
            for (int ni = 0; ni < 4; ni++)
                bfr[ni] = *(const bf16x8*)(Bs[cur] + (kk*4 + lk)*BN*8 + (wc*64 + ni*16 + lq)*8);
            #pragma unroll
            for (int mi = 0; mi < MI; mi++)
                #pragma unroll
                for (int ni = 0; ni < 4; ni++)
                    acc[mi][ni] = __builtin_amdgcn_mfma_f32_16x16x32_bf16(af[mi], bfr[ni], acc[mi][ni], 0, 0, 0);
        }
        cur ^= 1;
    }

    #pragma unroll
    for (int mi = 0; mi < MI; mi++) {
        #pragma unroll
        for (int ni = 0; ni < 4; ni++) {
            int n = bn + wc*64 + ni*16 + lq;
            int m0 = bm + wr*MI*16 + mi*16 + lk*4;
            if (EPI == 4) {
                if (n < 1536) {
                    const float* bb = (n < 768) ? bias : biasB;
                    int nn = (n < 768) ? n : (n - 768);
                    size_t base = (n < 768) ? 0 : ((size_t)S_ * 768);
                    #pragma unroll
                    for (int r = 0; r < 4; r++) {
                        int m = m0 + r;
                        if (m < M)
                            ((unsigned short*)outp)[base + (size_t)m*768 + nn] = f2bf(acc[mi][ni][r] + bb[nn]);
                    }
                } else {
                    if (m0 < M) {
                        float bv = biasC[n - 1536];
                        ushort4 pv;
                        pv.x = f2bf(acc[mi][ni][0] + bv);
                        pv.y = f2bf(acc[mi][ni][1] + bv);
                        pv.z = f2bf(acc[mi][ni][2] + bv);
                        pv.w = f2bf(acc[mi][ni][3] + bv);
                        *(ushort4*)((unsigned short*)outp2 + (size_t)(n - 1536)*S_ + m0) = pv;
                    }
                }
            } else {
                #pragma unroll
                for (int r = 0; r < 4; r++) {
                    int m = m0 + r;
                    if (m < M) {
                        float v = acc[mi][ni][r] + bias[n];
                        if (EPI == 1) {
                            v = 0.5f * v * (1.f + erff(v * 0.70710678f));
                            ((unsigned short*)outp)[(size_t)m*N + n] = f2bf(v);
                        } else {
                            size_t o = (size_t)m*N + n;
                            ((float*)outp)[o] = v*scale[n] + addend[o];
                        }
                    }
                }
            }
        }
    }
}

// ---------------- MFMA flash attention v6 (165.5 us, 4x confirmed) ----------------
__global__ __launch_bounds__(256) void attn_mfma6(const unsigned short* __restrict__ Q,
                                                  const unsigned short* __restrict__ Kb,
                                                  const unsigned short* __restrict__ Vt,
                                                  unsigned short* __restrict__ O)
{
    __shared__ __align__(16) unsigned short Ks[2][4096];   // [dg][kv][8]
    __shared__ __align__(16) unsigned short Vs[2][4096];   // [kvg][d][8]
    int tid = threadIdx.x;
    int w = tid >> 6, lane = tid & 63, lq = lane & 15, lk = lane >> 4;
    int h = blockIdx.y;
    int q0 = blockIdx.x * 128 + w * 32;

    bf16x8 qf[2][2];
    #pragma unroll
    for (int qi = 0; qi < 2; qi++) {
        int qr = q0 + qi*16 + lq; if (qr >= S_) qr = S_ - 1;
        #pragma unroll
        for (int ks = 0; ks < 2; ks++)
            qf[qi][ks] = *(const bf16x8*)(Q + (size_t)qr*C_ + h*64 + ks*32 + lk*8);
    }

    union { bf16x8 v; unsigned int u[4]; } ones;
    ones.u[0] = 0x3F803F80u; ones.u[1] = 0x3F803F80u;
    ones.u[2] = 0x3F803F80u; ones.u[3] = 0x3F803F80u;

    f32x4 oacc[2][4];
    #pragma unroll
    for (int qi = 0; qi < 2; qi++)
        #pragma unroll
        for (int df = 0; df < 4; df++) oacc[qi][df] = 0;
    f32x4 lacc[2];
    lacc[0] = 0; lacc[1] = 0;

    auto STAGE = [&](int buf, int t) {
        int kv0 = t * 64;
        #pragma unroll
        for (int u = 0; u < 4; u++) {
            int tt = w*4 + u;
            if (tt < 8)
                gload16(Kb + (size_t)(kv0 + lane)*C_ + h*64 + tt*8, Ks[buf] + tt*512);
            else
                gload16(Vt + (size_t)(h*64 + lane)*S_ + kv0 + (tt-8)*8, Vs[buf] + (tt-8)*512);
        }
    };

    auto BODY = [&](int buf) {
        f32x4 s[2][4];
        #pragma unroll
        for (int qi = 0; qi < 2; qi++)
            #pragma unroll
            for (int nf = 0; nf < 4; nf++) s[qi][nf] = -8.0f;
        __builtin_amdgcn_s_setprio(1);
        #pragma unroll
        for (int ks = 0; ks < 2; ks++) {
            #pragma unroll
            for (int nf = 0; nf < 4; nf++) {
                bf16x8 kf = *(const bf16x8*)(Ks[buf] + (ks*4 + lk)*512 + (nf*16 + lq)*8);
                #pragma unroll
                for (int qi = 0; qi < 2; qi++)
                    s[qi][nf] = __builtin_amdgcn_mfma_f32_16x16x32_bf16(kf, qf[qi][ks], s[qi][nf], 0, 0, 0);
            }
        }
        __builtin_amdgcn_s_setprio(0);

        unsigned int pk[2][8];
        #pragma unroll
        for (int qi = 0; qi < 2; qi++) {
            #pragma unroll
            for (int nf = 0; nf < 4; nf++) {
                float p0 = exp2f(s[qi][nf][0]);
                float p1 = exp2f(s[qi][nf][1]);
                float p2 = exp2f(s[qi][nf][2]);
                float p3 = exp2f(s[qi][nf][3]);
                pk[qi][nf*2+0] = cvtpk(p0, p1);
                pk[qi][nf*2+1] = cvtpk(p2, p3);
            }
        }

        __builtin_amdgcn_s_setprio(1);
        #pragma unroll
        for (int ks = 0; ks < 2; ks++) {
            union { bf16x8 v; unsigned int u[4]; } pb[2];
            #pragma unroll
            for (int qi = 0; qi < 2; qi++) {
                pb[qi].u[0] = pk[qi][4*ks+0]; pb[qi].u[1] = pk[qi][4*ks+1];
                pb[qi].u[2] = pk[qi][4*ks+2]; pb[qi].u[3] = pk[qi][4*ks+3];
                lacc[qi] = __builtin_amdgcn_mfma_f32_16x16x32_bf16(ones.v, pb[qi].v, lacc[qi], 0, 0, 0);
            }
            #pragma unroll
            for (int df = 0; df < 4; df++) {
                int d = df*16 + lq;
                union { bf16x8 v; unsigned long long dd[2]; } va;
                va.dd[0] = *(const unsigned long long*)(Vs[buf] + (4*ks + (lk>>1))*512 + d*8 + (lk&1)*4);
                va.dd[1] = *(const unsigned long long*)(Vs[buf] + (4*ks + 2 + (lk>>1))*512 + d*8 + (lk&1)*4);
                #pragma unroll
                for (int qi = 0; qi < 2; qi++)
                    oacc[qi][df] = __builtin_amdgcn_mfma_f32_16x16x32_bf16(va.v, pb[qi].v, oacc[qi][df], 0, 0, 0);
            }
        }
        __builtin_amdgcn_s_setprio(0);
    };

    // NT = 81: 40 unrolled pairs + peeled tail
    STAGE(0, 0);
    #pragma unroll 1
    for (int t = 0; t < 80; t += 2) {
        __syncthreads();
        STAGE(1, t + 1);
        BODY(0);
        __syncthreads();
        STAGE(0, t + 2);        // t+2 <= 80 always valid
        BODY(1);
    }
    __syncthreads();
    BODY(0);                    // tile 80

    #pragma unroll
    for (int qi = 0; qi < 2; qi++) {
        int q = q0 + qi*16 + lq;
        if (q < S_) {
            float rl = 1.f / lacc[qi][0];
            #pragma unroll
            for (int df = 0; df < 4; df++) {
                ushort4 pv;
                pv.x = f2bf(oacc[qi][df][0] * rl);
                pv.y = f2bf(oacc[qi][df][1] * rl);
                pv.z = f2bf(oacc[qi][df][2] * rl);
                pv.w = f2bf(oacc[qi][df][3] * rl);
                *(ushort4*)(O + (size_t)q*C_ + h*64 + df*16 + lk*4) = pv;
            }
        }
    }
}

extern "C" void kernel_launch(void* const* d_in, const int* in_sizes, int n_in,
                              void* d_out, int out_size, void* d_ws, size_t ws_size,
                              hipStream_t stream)
{
    const float* hidden = (const float*)d_in[0];
    const float* wq  = (const float*)d_in[1];
    const float* bq  = (const float*)d_in[2];
    const float* wk  = (const float*)d_in[3];
    const float* bk  = (const float*)d_in[4];
    const float* wv  = (const float*)d_in[5];
    const float* bv  = (const float*)d_in[6];
    const float* wo  = (const float*)d_in[7];
    const float* bo  = (const float*)d_in[8];
    const float* g1  = (const float*)d_in[9];
    const float* b1  = (const float*)d_in[10];
    const float* g2  = (const float*)d_in[11];
    const float* b2  = (const float*)d_in[12];
    const float* wf1 = (const float*)d_in[13];
    const float* bf1 = (const float*)d_in[14];
    const float* wf2 = (const float*)d_in[15];
    const float* bf2_ = (const float*)d_in[16];
    const float* ls1 = (const float*)d_in[17];
    const float* ls2 = (const float*)d_in[18];

    char* ws = (char*)d_ws;
    size_t off = 0;
    auto alloc = [&](size_t bytes) { char* p = ws + off; off += (bytes + 255) & ~(size_t)255; return p; };

    float* res1          = (float*)alloc((size_t)S_*C_*4);
    unsigned short* lnb  = (unsigned short*)alloc((size_t)S_*C_*2);
    unsigned short* qb   = (unsigned short*)alloc((size_t)S_*C_*2);  // qb,kb contiguous (fused out)
    unsigned short* kb   = (unsigned short*)alloc((size_t)S_*C_*2);
    unsigned short* vtb  = (unsigned short*)alloc((size_t)S_*C_*2);  // V^T [C_][S_]
    unsigned short* ob   = (unsigned short*)alloc((size_t)S_*C_*2);
    unsigned short* fc1b = qb;   // alias qb..ob (4*S*C*2 == S*FF*2), dead by fc1
    unsigned short* wqT  = (unsigned short*)alloc((size_t)C_*C_*2);  // wqT,wkT,wvT contiguous
    unsigned short* wkT  = (unsigned short*)alloc((size_t)C_*C_*2);
    unsigned short* wvT  = (unsigned short*)alloc((size_t)C_*C_*2);
    unsigned short* woT  = (unsigned short*)alloc((size_t)C_*C_*2);
    unsigned short* wf1T = (unsigned short*)alloc((size_t)C_*FF_*2);
    unsigned short* wf2T = (unsigned short*)alloc((size_t)C_*FF_*2);
    float* outb = (float*)d_out;

    hipLaunchKernelGGL(transpose_all, dim3(6912), dim3(256), 0, stream,
                       wq, wqT, wk, wkT, wv, wvT, wo, woT, wf1, wf1T, wf2, wf2T);
    hipLaunchKernelGGL(ln_k<float>, dim3(S_), dim3(256), 0, stream, hidden, g1, b1, lnb);
    hipLaunchKernelGGL((gemm_mfma<4,2,32>), dim3(2304/128, 41), dim3(256), 0, stream,
                       lnb, wqT, bq, bk, bv, (const float*)nullptr, (const float*)nullptr,
                       (void*)qb, (void*)vtb, S_, 2304, C_);
    hipLaunchKernelGGL(rope_k, dim3((S_*32 + 255)/256), dim3(256), 0, stream, qb, kb);
    hipLaunchKernelGGL(attn_mfma6, dim3((S_ + 127)/128, NH_), dim3(256), 0, stream,
                       qb, kb, vtb, ob);
    hipLaunchKernelGGL((gemm_mfma<2,1,64>), dim3(C_/64, 41), dim3(256), 0, stream,
                       ob, woT, bo, (const float*)nullptr, (const float*)nullptr, ls1, hidden,
                       (void*)res1, (void*)nullptr, S_, C_, C_);
    hipLaunchKernelGGL(ln_k<float>, dim3(S_), dim3(256), 0, stream, res1, g2, b2, lnb);
    hipLaunchKernelGGL((gemm_mfma<1,2,32>), dim3(FF_/128, 41), dim3(256), 0, stream,
                       lnb, wf1T, bf1, (const float*)nullptr, (const float*)nullptr,
                       (const float*)nullptr, (const float*)nullptr,
                       (void*)fc1b, (void*)nullptr, S_, FF_, C_);
    hipLaunchKernelGGL((gemm_mfma<2,1,64>), dim3(C_/64, 41), dim3(256), 0, stream,
                       fc1b, wf2T, bf2_, (const float*)nullptr, (const float*)nullptr, ls2, res1,
                       (void*)outb, (void*)nullptr, S_, C_, FF_);
    (void)in_sizes; (void)n_in; (void)out_size; (void)ws_size;
}